// Round 6
// baseline (10.535 us; speedup 1.0000x reference)
//
#include <hip/hip_runtime.h>
#include <math.h>

// Quanvolution hybrid classifier — closed-form feature map, 2 waves/image.
//
// Closed forms (fold rx(th0)@0, ry(th1)@1, rz(th2)@3 into the RY encoding;
// remaining gates act on disjoint wire pairs {0,2},{1,3}):
//   m0 = cos(th0) * cos(a0)
//   m1 = cos(a1 + th1)
//   m2 = cos(a2) * (A + B*cos(a0))
//   m3 = (C1 + C2*m1)*(K1*cos(a3) + K2*sin(a3)) + C5*(1-m1)*sin(a3)
// A=(cos th5+cos(th3+th5))/2, B=cos th0*(cos th5-cos(th3+th5))/2,
// C1=(1+cos th6)/2, C2=(1-cos th6)/2, K1=cos th4, K2=-sin th4*cos th2,
// C5=sin th6*sin th2/2.  rz(th7)@0 is a pure phase.
//
// Structure: block = 512 threads = 8 waves = 4 images; wave pair (2i,2i+1)
// splits image i's 196 patches into halves of 98. Doubles occupancy
// (8 -> 16 waves/CU) vs one-wave-per-image to hide load latency. Per-wave
// DPP reduction -> 10 uniform partials -> 320B LDS -> even wave combines,
// softmaxes, stores.

__device__ __forceinline__ float wave_sum_dpp(float v) {
#define DPP_ADD(CTRL, RMASK)                                                  \
    v += __int_as_float(__builtin_amdgcn_update_dpp(                          \
        0, __float_as_int(v), (CTRL), (RMASK), 0xf, true))
    DPP_ADD(0x111, 0xf);   // row_shr:1
    DPP_ADD(0x112, 0xf);   // row_shr:2
    DPP_ADD(0x114, 0xf);   // row_shr:4
    DPP_ADD(0x118, 0xf);   // row_shr:8  -> lanes 15/31/47/63 hold row sums
    DPP_ADD(0x142, 0xa);   // row_bcast:15
    DPP_ADD(0x143, 0xc);   // row_bcast:31 -> lane 63 holds the wave total
#undef DPP_ADD
    return __int_as_float(__builtin_amdgcn_readlane(__float_as_int(v), 63));
}

__global__ __launch_bounds__(512) void quanv_fused_kernel(
    const float* __restrict__ xin,   // (B, 784)
    const float* __restrict__ theta, // (8,)
    const float* __restrict__ Wm,    // (10, 784)
    const float* __restrict__ bv,    // (10,)
    float* __restrict__ out,         // (B, 10) log-softmax
    int B)
{
    __shared__ float part[8][10];

    const int t = threadIdx.x;
    const int w = t >> 6, l = t & 63;
    const int imgRaw = blockIdx.x * 4 + (w >> 1);
    const int img = (imgRaw < B) ? imgRaw : (B - 1);   // clamp; barrier stays uniform
    const int h = w & 1;                                // half: patches [h*98, h*98+98)

    const float* ib = xin + (size_t)img * 784;
    const int p0 = h * 98 + l;
    const bool two = (l < 34);                          // second patch p0+64
    const int p1 = p0 + 64;

    // ---- issue x loads first ----
    float2 rA0, rB0, rA1, rB1;
    {
        const int pi = p0 / 14, pj = p0 % 14;
        const float* pr = ib + pi * 56 + pj * 2;
        rA0 = *(const float2*)pr;
        rB0 = *(const float2*)(pr + 28);
    }
    if (two) {
        const int pi = p1 / 14, pj = p1 % 14;
        const float* pr = ib + pi * 56 + pj * 2;
        rA1 = *(const float2*)pr;
        rB1 = *(const float2*)(pr + 28);
    }

    // ---- theta-derived constants, per lane, hardware trig (args ~N(0,1)) ----
    const float t0 = theta[0], th1 = theta[1], t2 = theta[2], t3 = theta[3];
    const float t4 = theta[4], t5 = theta[5], t6 = theta[6];
    const float c5g = __cosf(t5), c35 = __cosf(t3 + t5);
    const float c6 = __cosf(t6), s6 = __sinf(t6);
    const float k0 = __cosf(t0);
    const float A  = 0.5f * (c5g + c35);
    const float Bc = 0.5f * k0 * (c5g - c35);
    const float C1 = 0.5f * (1.f + c6);
    const float C2 = 0.5f * (1.f - c6);
    const float K1 = __cosf(t4);
    const float K2 = -__sinf(t4) * __cosf(t2);
    const float C5 = 0.5f * s6 * __sinf(t2);

    auto featf = [&](float2 a, float2 b) -> float4 {
        const float ca0 = __cosf(a.x);
        const float u   = __cosf(a.y + th1);            // m1
        const float ca2 = __cosf(b.x);
        float sa3, ca3;
        __sincosf(b.y, &sa3, &ca3);
        const float m0 = k0 * ca0;
        const float m2 = ca2 * fmaf(Bc, ca0, A);
        const float zu = fmaf(K1, ca3, K2 * sa3);
        const float m3 = fmaf(fmaf(C2, u, C1), zu, C5 * sa3 * (1.f - u));
        return make_float4(m0, u, m2, m3);
    };

    // ---- GEMV over this lane's patches ----
    float acc[10];
#pragma unroll
    for (int c = 0; c < 10; ++c) acc[c] = 0.f;

    const float4* W4 = (const float4*)Wm;   // [10][196] float4
    {
        const float4 f = featf(rA0, rB0);
#pragma unroll
        for (int c = 0; c < 10; ++c) {
            const float4 wv = W4[c * 196 + p0];
            acc[c] = fmaf(f.w, wv.w, fmaf(f.z, wv.z,
                     fmaf(f.y, wv.y, fmaf(f.x, wv.x, acc[c]))));
        }
    }
    if (two) {
        const float4 f = featf(rA1, rB1);
#pragma unroll
        for (int c = 0; c < 10; ++c) {
            const float4 wv = W4[c * 196 + p1];
            acc[c] = fmaf(f.w, wv.w, fmaf(f.z, wv.z,
                     fmaf(f.y, wv.y, fmaf(f.x, wv.x, acc[c]))));
        }
    }

    // ---- per-wave DPP reduction -> 10 wave-uniform partial logits ----
    float partial[10];
#pragma unroll
    for (int c = 0; c < 10; ++c) partial[c] = wave_sum_dpp(acc[c]);

    // park partials in LDS (lanes 0..9, value selected by cndmask chain)
    if (l < 10) {
        float v = partial[9];
#pragma unroll
        for (int c = 8; c >= 0; --c) v = (l == c) ? partial[c] : v;
        part[w][l] = v;
    }
    __syncthreads();

    // ---- even wave of each pair: combine halves, softmax, store ----
    if (h == 0) {
        float logit[10];
#pragma unroll
        for (int c = 0; c < 10; ++c)
            logit[c] = part[w][c] + part[w + 1][c] + bv[c];

        float mx = -1e30f;
#pragma unroll
        for (int c = 0; c < 10; ++c) mx = fmaxf(mx, logit[c]);
        float sum = 0.f;
#pragma unroll
        for (int c = 0; c < 10; ++c) sum += __expf(logit[c] - mx);
        const float ls = __logf(sum);

        if (l < 10 && imgRaw < B) {
            float v = logit[9];
#pragma unroll
            for (int c = 8; c >= 0; --c) v = (l == c) ? logit[c] : v;
            out[(size_t)imgRaw * 10 + l] = v - mx - ls;
        }
    }
}

extern "C" void kernel_launch(void* const* d_in, const int* in_sizes, int n_in,
                              void* d_out, int out_size, void* d_ws, size_t ws_size,
                              hipStream_t stream) {
    const float* x     = (const float*)d_in[0];
    const float* theta = (const float*)d_in[1];
    const float* W     = (const float*)d_in[2];
    const float* bias  = (const float*)d_in[3];
    float* out         = (float*)d_out;

    const int B = in_sizes[0] / 784;
    const int grid = (B + 3) / 4;
    quanv_fused_kernel<<<grid, 512, 0, stream>>>(x, theta, W, bias, out, B);
}